// Round 1
// baseline (353.090 us; speedup 1.0000x reference)
//
#include <hip/hip_runtime.h>
#include <hip/hip_fp16.h>

// FixedPointLSTMCell on MI355X.
// Exactness argument: all fake_quant'd operands are integers at scale 2^8;
// we compute the GEMMs on the scaled integers in f16 MFMA (exact: |xi|<2048,
// |wi|<128, all partial sums < 2^24 in the fp32 accumulator), then replicate
// the reference's fp32 elementwise ops exactly (rintf = round-half-even,
// correctly-rounded /6.0f, exact dyadic scaling).

typedef _Float16 half8 __attribute__((ext_vector_type(8)));
typedef float f32x4 __attribute__((ext_vector_type(4)));

#define AS1 __attribute__((address_space(1)))
#define AS3 __attribute__((address_space(3)))

__device__ __forceinline__ void gload16(const void* g, void* l) {
  __builtin_amdgcn_global_load_lds((const AS1 void*)g, (AS3 void*)l, 16, 0, 0);
}

__device__ __forceinline__ float quant256(float v) {
  // clip(round(v*256), +-32767); *256 is exact (exponent shift), rintf = half-even
  float q = rintf(v * 256.0f);
  return fminf(fmaxf(q, -32767.0f), 32767.0f);
}

// ---------------- prep: quantize inputs to integer-valued fp16 ----------------
__global__ __launch_bounds__(256) void prep_kernel(
    const float* __restrict__ x, const float* __restrict__ h,
    const float* __restrict__ Wi, const float* __restrict__ Wh,
    const float* __restrict__ bi, const float* __restrict__ bh,
    __half* __restrict__ xq, __half* __restrict__ hq,
    __half* __restrict__ wiq, __half* __restrict__ whq,
    float* __restrict__ biq, float* __restrict__ bhq) {
  const int i = blockIdx.x * 256 + threadIdx.x;  // 0 .. 2097151, 4 elems each
  {
    const float4 vx = ((const float4*)x)[i];
    const float4 vh = ((const float4*)h)[i];
    union { __half hh[4]; uint2 u; } ux, uh;
    ux.hh[0] = __half(quant256(vx.x)); ux.hh[1] = __half(quant256(vx.y));
    ux.hh[2] = __half(quant256(vx.z)); ux.hh[3] = __half(quant256(vx.w));
    uh.hh[0] = __half(quant256(vh.x)); uh.hh[1] = __half(quant256(vh.y));
    uh.hh[2] = __half(quant256(vh.z)); uh.hh[3] = __half(quant256(vh.w));
    ((uint2*)xq)[i] = ux.u;
    ((uint2*)hq)[i] = uh.u;
  }
  if (i < 262144) {  // weights: 2048*512/4
    const float4 vi4 = ((const float4*)Wi)[i];
    const float4 vh4 = ((const float4*)Wh)[i];
    union { __half hh[4]; uint2 u; } uwi, uwh;
    uwi.hh[0] = __half(quant256(vi4.x)); uwi.hh[1] = __half(quant256(vi4.y));
    uwi.hh[2] = __half(quant256(vi4.z)); uwi.hh[3] = __half(quant256(vi4.w));
    uwh.hh[0] = __half(quant256(vh4.x)); uwh.hh[1] = __half(quant256(vh4.y));
    uwh.hh[2] = __half(quant256(vh4.z)); uwh.hh[3] = __half(quant256(vh4.w));
    ((uint2*)wiq)[i] = uwi.u;
    ((uint2*)whq)[i] = uwh.u;
  }
  if (i < 512) {  // biases: 2048/4 — store scaled-int bias as float
    #pragma unroll
    for (int j = 0; j < 4; ++j) {
      biq[i * 4 + j] = quant256(bi[i * 4 + j]);
      bhq[i * 4 + j] = quant256(bh[i * 4 + j]);
    }
  }
}

// ---------------- fused dual-GEMM + LSTM gates ----------------
// Tile: BM=128 rows x BN=64 h-cols, 4 waves (2x2), BK=64, f16 mfma 16x16x32.
// Gate loop g=0..3: acc_i = Xq @ W_ih[g-block]^T, acc_h = Hq @ W_hh[g-block]^T.
// LDS layout [rows][64 halves], 16B-block XOR swizzle: blk ^= (row&7)
// applied on BOTH the global source of global_load_lds and the ds_read.
__global__ __launch_bounds__(256) void lstm_gemm(
    const __half* __restrict__ xq, const __half* __restrict__ hq,
    const __half* __restrict__ wiq, const __half* __restrict__ whq,
    const float* __restrict__ biq, const float* __restrict__ bhq,
    const float* __restrict__ cprev,
    float* __restrict__ out_h, float* __restrict__ out_c) {
  __shared__ __align__(16) __half sX[128 * 64];   // 16 KB
  __shared__ __align__(16) __half sH[128 * 64];   // 16 KB
  __shared__ __align__(16) __half sWi[64 * 64];   //  8 KB
  __shared__ __align__(16) __half sWh[64 * 64];   //  8 KB

  const int tid = threadIdx.x;
  const int lane = tid & 63;
  const int wid = tid >> 6;
  const int wm = wid >> 1, wn = wid & 1;
  const int l15 = lane & 15;
  const int l4 = lane >> 4;

  const int bid = blockIdx.x;
  const int tileM = bid >> 3;   // 128 M-tiles
  const int tileN = bid & 7;    // 8 N-tiles
  const int row0 = tileM * 128;
  const int col0 = tileN * 64;

  float vi[32], vf[32], th[32];

  for (int g = 0; g < 4; ++g) {
    f32x4 accA[4][2], accB[4][2];
    const f32x4 zero = {0.f, 0.f, 0.f, 0.f};
    #pragma unroll
    for (int m = 0; m < 4; ++m)
      #pragma unroll
      for (int n = 0; n < 2; ++n) { accA[m][n] = zero; accB[m][n] = zero; }

    const int wrow0 = g * 512 + col0;  // weight-row base for this gate block

    for (int kk = 0; kk < 512; kk += 64) {
      __syncthreads();  // prior compute done before overwriting LDS
      // stage X,H: 16 chunks of 1KB each; this wave does 4
      #pragma unroll
      for (int i2 = 0; i2 < 4; ++i2) {
        const int c = wid * 4 + i2;
        const int q = c * 64 + lane;
        const int r = q >> 3, b = q & 7;
        const int goff = (row0 + r) * 512 + kk + ((b ^ (r & 7)) << 3);
        gload16(xq + goff, (char*)sX + c * 1024);
        gload16(hq + goff, (char*)sH + c * 1024);
      }
      // stage Wi,Wh: 8 chunks each; this wave does 2
      #pragma unroll
      for (int i2 = 0; i2 < 2; ++i2) {
        const int c = wid * 2 + i2;
        const int q = c * 64 + lane;
        const int r = q >> 3, b = q & 7;
        const int goff = (wrow0 + r) * 512 + kk + ((b ^ (r & 7)) << 3);
        gload16(wiq + goff, (char*)sWi + c * 1024);
        gload16(whq + goff, (char*)sWh + c * 1024);
      }
      __syncthreads();  // compiler drains vmcnt before barrier

      #pragma unroll
      for (int ks = 0; ks < 2; ++ks) {
        half8 ax[4], ah[4], bwi[2], bwh[2];
        #pragma unroll
        for (int m = 0; m < 4; ++m) {
          const int r = wm * 64 + m * 16 + l15;
          const int kb = ks * 4 + l4;
          const int off = r * 64 + ((kb ^ (r & 7)) << 3);
          ax[m] = *(const half8*)&sX[off];
          ah[m] = *(const half8*)&sH[off];
        }
        #pragma unroll
        for (int n = 0; n < 2; ++n) {
          const int cr = wn * 32 + n * 16 + l15;
          const int kb = ks * 4 + l4;
          const int off = cr * 64 + ((kb ^ (cr & 7)) << 3);
          bwi[n] = *(const half8*)&sWi[off];
          bwh[n] = *(const half8*)&sWh[off];
        }
        #pragma unroll
        for (int m = 0; m < 4; ++m)
          #pragma unroll
          for (int n = 0; n < 2; ++n) {
            accA[m][n] = __builtin_amdgcn_mfma_f32_16x16x32_f16(ax[m], bwi[n], accA[m][n], 0, 0, 0);
            accB[m][n] = __builtin_amdgcn_mfma_f32_16x16x32_f16(ah[m], bwh[n], accB[m][n], 0, 0, 0);
          }
      }
    }

    // ---- epilogue for gate g ----
    float bvi[2], bvh[2];
    #pragma unroll
    for (int n = 0; n < 2; ++n) {
      const int C = col0 + wn * 32 + n * 16 + l15;
      bvi[n] = biq[g * 512 + C];
      bvh[n] = bhq[g * 512 + C];
    }
    #pragma unroll
    for (int m = 0; m < 4; ++m)
      #pragma unroll
      for (int n = 0; n < 2; ++n)
        #pragma unroll
        for (int j = 0; j < 4; ++j) {
          const int e = (m * 2 + n) * 4 + j;
          // y*256 = acc/256 + b_int (all exact); round-half-even; clip
          float gi = rintf(accA[m][n][j] * (1.0f / 256.0f) + bvi[n]);
          gi = fminf(fmaxf(gi, -32767.f), 32767.f);
          float gh = rintf(accB[m][n][j] * (1.0f / 256.0f) + bvh[n]);
          gh = fminf(fmaxf(gh, -32767.f), 32767.f);
          const float s = gi + gh;  // gate pre-activation * 256 (exact int)
          if (g == 2) {
            // hard_tanh + fake_quant == clip(s, -256, 256) exactly
            const float gv = fminf(fmaxf(s, -256.f), 256.f);
            const int R = row0 + wm * 64 + m * 16 + l4 * 4 + j;
            const int C = col0 + wn * 32 + n * 16 + l15;
            const float cpq = quant256(cprev[R * 512 + C]);
            const float cnum = vf[e] * cpq + vi[e] * gv;  // exact int, scale 2^16
            const float cval = cnum * (1.0f / 65536.0f);
            out_c[R * 512 + C] = cval;
            const float tt = fminf(fmaxf(cval, -1.0f), 1.0f);
            th[e] = rintf(tt * 256.0f);  // fake_quant(hard_tanh(c)) * 256
          } else {
            // hard_sigmoid then fake_quant, exactly as reference fp32 op order
            const float u = s * (1.0f / 256.0f);        // exact
            float t = u / 6.0f + 0.5f;                  // correctly-rounded div
            t = fminf(fmaxf(t, 0.0f), 1.0f);
            const float v = rintf(t * 256.0f);          // gate * 256
            if (g == 0) vi[e] = v;
            else if (g == 1) vf[e] = v;
            else {  // g == 3: output gate -> h
              const int R = row0 + wm * 64 + m * 16 + l4 * 4 + j;
              const int C = col0 + wn * 32 + n * 16 + l15;
              out_h[R * 512 + C] = (v * th[e]) * (1.0f / 65536.0f);
            }
          }
        }
  }
}

extern "C" void kernel_launch(void* const* d_in, const int* in_sizes, int n_in,
                              void* d_out, int out_size, void* d_ws, size_t ws_size,
                              hipStream_t stream) {
  const float* x      = (const float*)d_in[0];
  const float* h_prev = (const float*)d_in[1];
  const float* c_prev = (const float*)d_in[2];
  const float* W_ih   = (const float*)d_in[3];
  const float* b_ih   = (const float*)d_in[4];
  const float* W_hh   = (const float*)d_in[5];
  const float* b_hh   = (const float*)d_in[6];
  float* out = (float*)d_out;

  char* ws = (char*)d_ws;
  __half* xqp  = (__half*)(ws);
  __half* hqp  = (__half*)(ws + (16u << 20));
  __half* wiqp = (__half*)(ws + (32u << 20));
  __half* whqp = (__half*)(ws + (34u << 20));
  float*  biqp = (float*)(ws + (36u << 20));
  float*  bhqp = (float*)(ws + (36u << 20) + 8192);

  prep_kernel<<<8192, 256, 0, stream>>>(x, h_prev, W_ih, W_hh, b_ih, b_hh,
                                        xqp, hqp, wiqp, whqp, biqp, bhqp);

  lstm_gemm<<<1024, 256, 0, stream>>>(xqp, hqp, wiqp, whqp, biqp, bhqp,
                                      c_prev, out, out + 8388608);
}

// Round 2
// 103.205 us; speedup vs baseline: 3.4212x; 3.4212x over previous
//
#include <hip/hip_runtime.h>
#include <hip/hip_fp16.h>

// FixedPointLSTMCell on MI355X — R2: gate-fused single-pass dual GEMM.
// Exactness: all fake_quant'd operands are integers at scale 2^8; GEMMs on
// scaled integers in f16 MFMA (exact, fp32 accum < 2^24), elementwise ops
// replicate reference fp32 exactly (rintf = half-even, correctly-rounded /6).

typedef _Float16 half8 __attribute__((ext_vector_type(8)));
typedef float f32x4 __attribute__((ext_vector_type(4)));

#define AS1 __attribute__((address_space(1)))
#define AS3 __attribute__((address_space(3)))

__device__ __forceinline__ void gload16(const void* g, void* l) {
  __builtin_amdgcn_global_load_lds((const AS1 void*)g, (AS3 void*)l, 16, 0, 0);
}

__device__ __forceinline__ float quant256(float v) {
  float q = rintf(v * 256.0f);
  return fminf(fmaxf(q, -32767.0f), 32767.0f);
}

// ---------------- prep: quantize inputs to integer-valued fp16 ----------------
__global__ __launch_bounds__(256) void prep_kernel(
    const float* __restrict__ x, const float* __restrict__ h,
    const float* __restrict__ Wi, const float* __restrict__ Wh,
    const float* __restrict__ bi, const float* __restrict__ bh,
    __half* __restrict__ xq, __half* __restrict__ hq,
    __half* __restrict__ wiq, __half* __restrict__ whq,
    float* __restrict__ biq, float* __restrict__ bhq) {
  const int i = blockIdx.x * 256 + threadIdx.x;  // 4 elems each
  {
    const float4 vx = ((const float4*)x)[i];
    const float4 vh = ((const float4*)h)[i];
    union { __half hh[4]; uint2 u; } ux, uh;
    ux.hh[0] = __half(quant256(vx.x)); ux.hh[1] = __half(quant256(vx.y));
    ux.hh[2] = __half(quant256(vx.z)); ux.hh[3] = __half(quant256(vx.w));
    uh.hh[0] = __half(quant256(vh.x)); uh.hh[1] = __half(quant256(vh.y));
    uh.hh[2] = __half(quant256(vh.z)); uh.hh[3] = __half(quant256(vh.w));
    ((uint2*)xq)[i] = ux.u;
    ((uint2*)hq)[i] = uh.u;
  }
  if (i < 262144) {  // weights: 2048*512/4
    const float4 vi4 = ((const float4*)Wi)[i];
    const float4 vh4 = ((const float4*)Wh)[i];
    union { __half hh[4]; uint2 u; } uwi, uwh;
    uwi.hh[0] = __half(quant256(vi4.x)); uwi.hh[1] = __half(quant256(vi4.y));
    uwi.hh[2] = __half(quant256(vi4.z)); uwi.hh[3] = __half(quant256(vi4.w));
    uwh.hh[0] = __half(quant256(vh4.x)); uwh.hh[1] = __half(quant256(vh4.y));
    uwh.hh[2] = __half(quant256(vh4.z)); uwh.hh[3] = __half(quant256(vh4.w));
    ((uint2*)wiq)[i] = uwi.u;
    ((uint2*)whq)[i] = uwh.u;
  }
  if (i < 512) {  // biases (scaled-int, as float)
    #pragma unroll
    for (int j = 0; j < 4; ++j) {
      biq[i * 4 + j] = quant256(bi[i * 4 + j]);
      bhq[i * 4 + j] = quant256(bh[i * 4 + j]);
    }
  }
}

// ---------------- gate-fused dual-GEMM + LSTM cell ----------------
// Block: 128 rows x 32 h-cols x ALL 4 gates (128 weight rows, gate-major:
// LDS weight row wr = g*32 + c_local  <->  global row g*512 + col0 + c_local).
// 4 waves split M only (32 rows each); each wave spans all 128 weight rows
// (8 n-frags). Thread's n-frag n holds gate n>>1, col (n&1)*16 + l15 — all
// four gates of a column live in the same thread: fully fused epilogue.
// BK=64, single LDS buffer, 16B-block XOR swizzle on both sides.
__global__ __launch_bounds__(256, 2) void lstm_gemm(
    const __half* __restrict__ xq, const __half* __restrict__ hq,
    const __half* __restrict__ wiq, const __half* __restrict__ whq,
    const float* __restrict__ biq, const float* __restrict__ bhq,
    const float* __restrict__ cprev,
    float* __restrict__ out_h, float* __restrict__ out_c) {
  __shared__ __align__(16) __half sX[128 * 64];   // 16 KB
  __shared__ __align__(16) __half sH[128 * 64];   // 16 KB
  __shared__ __align__(16) __half sWi[128 * 64];  // 16 KB
  __shared__ __align__(16) __half sWh[128 * 64];  // 16 KB

  const int tid = threadIdx.x;
  const int lane = tid & 63;
  const int wid = tid >> 6;         // wave id 0..3 = M split
  const int l15 = lane & 15;
  const int l4 = lane >> 4;

  // XCD-aware bijective swizzle (2048 % 8 == 0): each XCD gets 16 contiguous
  // M-slabs -> X/H tiles L2-local per XCD.
  const int bid = blockIdx.x;
  const int lbid = (bid & 7) * 256 + (bid >> 3);
  const int tileM = lbid >> 4;      // 0..127
  const int tileN = lbid & 15;      // 0..15
  const int row0 = tileM * 128;
  const int col0 = tileN * 32;

  f32x4 accA[2][8], accB[2][8];
  const f32x4 zero = {0.f, 0.f, 0.f, 0.f};
  #pragma unroll
  for (int m = 0; m < 2; ++m)
    #pragma unroll
    for (int n = 0; n < 8; ++n) { accA[m][n] = zero; accB[m][n] = zero; }

  for (int kk = 0; kk < 512; kk += 64) {
    __syncthreads();  // prior compute done before overwriting LDS
    // stage X,H: 16 chunks of 1KB each buffer; this wave does 4
    #pragma unroll
    for (int i2 = 0; i2 < 4; ++i2) {
      const int c = wid * 4 + i2;
      const int r = c * 8 + (lane >> 3);
      const int b = lane & 7;
      const int goff = (row0 + r) * 512 + kk + ((b ^ (r & 7)) << 3);
      gload16(xq + goff, (char*)sX + c * 1024);
      gload16(hq + goff, (char*)sH + c * 1024);
    }
    // stage Wi,Wh: gate-major row mapping
    #pragma unroll
    for (int i2 = 0; i2 < 4; ++i2) {
      const int c = wid * 4 + i2;
      const int r = c * 8 + (lane >> 3);          // LDS row 0..127
      const int b = lane & 7;
      const int gr = (r >> 5) * 512 + col0 + (r & 31);  // global weight row
      const int goff = gr * 512 + kk + ((b ^ (r & 7)) << 3);
      gload16(wiq + goff, (char*)sWi + c * 1024);
      gload16(whq + goff, (char*)sWh + c * 1024);
    }
    __syncthreads();  // compiler drains vmcnt before barrier

    #pragma unroll
    for (int ks = 0; ks < 2; ++ks) {
      const int kb = ks * 4 + l4;
      half8 ax[2], ah[2];
      #pragma unroll
      for (int m = 0; m < 2; ++m) {
        const int r = wid * 32 + m * 16 + l15;
        const int off = r * 64 + ((kb ^ (r & 7)) << 3);
        ax[m] = *(const half8*)&sX[off];
        ah[m] = *(const half8*)&sH[off];
      }
      #pragma unroll
      for (int n = 0; n < 8; ++n) {
        const int wr = n * 16 + l15;
        const int off = wr * 64 + ((kb ^ (wr & 7)) << 3);
        const half8 bwi = *(const half8*)&sWi[off];
        const half8 bwh = *(const half8*)&sWh[off];
        #pragma unroll
        for (int m = 0; m < 2; ++m) {
          accA[m][n] = __builtin_amdgcn_mfma_f32_16x16x32_f16(ax[m], bwi, accA[m][n], 0, 0, 0);
          accB[m][n] = __builtin_amdgcn_mfma_f32_16x16x32_f16(ah[m], bwh, accB[m][n], 0, 0, 0);
        }
      }
    }
  }

  // ---- fused epilogue: all 4 gates in-thread ----
  float bvi[8], bvh[8];
  #pragma unroll
  for (int n = 0; n < 8; ++n) {
    const int gwr = (n >> 1) * 512 + col0 + ((n & 1) * 16) + l15;
    bvi[n] = biq[gwr];
    bvh[n] = bhq[gwr];
  }

  #pragma unroll
  for (int m = 0; m < 2; ++m)
    #pragma unroll
    for (int cb = 0; cb < 2; ++cb)
      #pragma unroll
      for (int j = 0; j < 4; ++j) {
        float s[4];
        #pragma unroll
        for (int g = 0; g < 4; ++g) {
          const int n = g * 2 + cb;
          float gi = rintf(accA[m][n][j] * (1.0f / 256.0f) + bvi[n]);
          gi = fminf(fmaxf(gi, -32767.f), 32767.f);
          float gh = rintf(accB[m][n][j] * (1.0f / 256.0f) + bvh[n]);
          gh = fminf(fmaxf(gh, -32767.f), 32767.f);
          s[g] = gi + gh;  // pre-activation * 256 (exact int)
        }
        // hard_sigmoid gates (i, f, o): u = s/256; t = clip(u/6+0.5); v = rint(t*256)
        float vi, vf, vo, gg;
        {
          float t = (s[0] * (1.0f / 256.0f)) / 6.0f + 0.5f;
          vi = rintf(fminf(fmaxf(t, 0.0f), 1.0f) * 256.0f);
        }
        {
          float t = (s[1] * (1.0f / 256.0f)) / 6.0f + 0.5f;
          vf = rintf(fminf(fmaxf(t, 0.0f), 1.0f) * 256.0f);
        }
        gg = fminf(fmaxf(s[2], -256.f), 256.f);  // hard_tanh+quant == clip
        {
          float t = (s[3] * (1.0f / 256.0f)) / 6.0f + 0.5f;
          vo = rintf(fminf(fmaxf(t, 0.0f), 1.0f) * 256.0f);
        }
        const int R = row0 + wid * 32 + m * 16 + l4 * 4 + j;
        const int C = col0 + cb * 16 + l15;
        const float cpq = quant256(cprev[R * 512 + C]);
        const float cnum = vf * cpq + vi * gg;        // exact int, scale 2^16
        const float cval = cnum * (1.0f / 65536.0f);
        out_c[R * 512 + C] = cval;
        const float tt = fminf(fmaxf(cval, -1.0f), 1.0f);
        const float th = rintf(tt * 256.0f);
        out_h[R * 512 + C] = (vo * th) * (1.0f / 65536.0f);
      }
}

extern "C" void kernel_launch(void* const* d_in, const int* in_sizes, int n_in,
                              void* d_out, int out_size, void* d_ws, size_t ws_size,
                              hipStream_t stream) {
  const float* x      = (const float*)d_in[0];
  const float* h_prev = (const float*)d_in[1];
  const float* c_prev = (const float*)d_in[2];
  const float* W_ih   = (const float*)d_in[3];
  const float* b_ih   = (const float*)d_in[4];
  const float* W_hh   = (const float*)d_in[5];
  const float* b_hh   = (const float*)d_in[6];
  float* out = (float*)d_out;

  char* ws = (char*)d_ws;
  __half* xqp  = (__half*)(ws);
  __half* hqp  = (__half*)(ws + (16u << 20));
  __half* wiqp = (__half*)(ws + (32u << 20));
  __half* whqp = (__half*)(ws + (34u << 20));
  float*  biqp = (float*)(ws + (36u << 20));
  float*  bhqp = (float*)(ws + (36u << 20) + 8192);

  prep_kernel<<<8192, 256, 0, stream>>>(x, h_prev, W_ih, W_hh, b_ih, b_hh,
                                        xqp, hqp, wiqp, whqp, biqp, bhqp);

  lstm_gemm<<<2048, 256, 0, stream>>>(xqp, hqp, wiqp, whqp, biqp, bhqp,
                                      c_prev, out, out + 8388608);
}